// Round 12
// baseline (290.819 us; speedup 1.0000x reference)
//
#include <hip/hip_runtime.h>

typedef __attribute__((ext_vector_type(8))) short bf16x8;
typedef __attribute__((ext_vector_type(16))) float f32x16;
typedef __attribute__((ext_vector_type(8))) unsigned short ushort8;

#define N_BLADES 32
#define B_DIM 1024
#define IN_DIM 256
#define OUT_DIM 256
#define K_DIM (IN_DIM * N_BLADES)   // 8192
#define N_DIM (OUT_DIM * N_BLADES)  // 8192

// ---------- helpers ----------

__device__ __forceinline__ unsigned short f2bf(float f) {
    unsigned int u = __float_as_uint(f);
    u = (u + 0x7fff + ((u >> 16) & 1)) >> 16;   // RNE
    return (unsigned short)u;
}

__device__ __forceinline__ float gp_sign(int a, int b) {
    int swaps = 0;
#pragma unroll
    for (int i = 0; i < 5; ++i) {
        int mask = (~((1 << (i + 1)) - 1)) & 31;
        swaps += ((b >> i) & 1) * __popc(a & mask);
    }
    float s = (swaps & 1) ? -1.0f : 1.0f;
    if (a & b & 16) s = -s;
    return s;
}

__device__ __forceinline__ void gload_lds16(const void* g, void* l) {
    __builtin_amdgcn_global_load_lds(
        (const __attribute__((address_space(1))) unsigned int*)g,
        (__attribute__((address_space(3))) unsigned int*)l, 16, 0, 0);
}

#define FENCE() asm volatile("" ::: "memory")
#define BAR()    { FENCE(); __builtin_amdgcn_s_barrier(); FENCE(); }
#define SCHED0() __builtin_amdgcn_sched_barrier(0)
#define LGKM(n)  { asm volatile("s_waitcnt lgkmcnt(" #n ")" ::: "memory"); }
#define VMC(n)   { asm volatile("s_waitcnt vmcnt(" #n ")" ::: "memory"); }

// ---------- prep: cast x fp32 -> bf16 into TRANSPOSED layout xb2[kt][b][128B] ----------
// octet (kt, b, o) holds x[b][kt*64 + o*8 .. +8) as bf16. A k-tile panel for a
// 128-row M-block is kt*131072 + row*128: dense 16KB -> L1-friendly direct loads.
__global__ __launch_bounds__(256) void cast_x2_kernel(const float* __restrict__ x,
                                                      unsigned short* __restrict__ xb2) {
    int t = blockIdx.x * 256 + threadIdx.x;    // 1,048,576 octets
    int o  = t & 7;
    int b  = (t >> 3) & 1023;
    int kt = t >> 13;
    const float4* src = (const float4*)(x + (long)b * K_DIM + kt * 64 + o * 8);
    float4 a = src[0], c = src[1];
    ushort8 pk;
    pk[0] = f2bf(a.x); pk[1] = f2bf(a.y); pk[2] = f2bf(a.z); pk[3] = f2bf(a.w);
    pk[4] = f2bf(c.x); pk[5] = f2bf(c.y); pk[6] = f2bf(c.z); pk[7] = f2bf(c.w);
    *(ushort8*)(xb2 + ((size_t)kt * 8192 + b * 8 + o) * 8) = pk;
}

// ---------- prep: cast + permute w into staged order (unchanged, known-good) ----------
__global__ __launch_bounds__(256) void cast_w_perm_kernel(const float* __restrict__ w,
                                                          unsigned short* __restrict__ wb2) {
    int t = blockIdx.x * 256 + threadIdx.x;    // 262144 octets
    int o31   = t & 31;
    int c16   = (t >> 5) & 7;
    int panel = (t >> 8) & 7;
    int kt    = t >> 11;
    int o  = panel * 32 + o31;
    int k0 = kt * 64 + c16 * 8;
    const float4* src = (const float4*)(w + (long)o * K_DIM + k0);
    float4 a = src[0], b = src[1];
    ushort8 pk;
    pk[0] = f2bf(a.x); pk[1] = f2bf(a.y); pk[2] = f2bf(a.z); pk[3] = f2bf(a.w);
    pk[4] = f2bf(b.x); pk[5] = f2bf(b.y); pk[6] = f2bf(b.z); pk[7] = f2bf(b.w);
    *(ushort8*)(wb2 + (size_t)t * 8) = pk;
}

// ---------- uniform-j XOR shuffle + sign mask on a bf16 octet (unchanged) ----------
__device__ __forceinline__ bf16x8 shuffle_sign(bf16x8 v, int jx,
                                               unsigned int m0, unsigned int m1,
                                               unsigned int m2, unsigned int m3) {
    union { bf16x8 v8; unsigned int w[4]; } a, b;
    a.v8 = v;
    int s = jx >> 1;
    unsigned int t0 = (s & 1) ? a.w[1] : a.w[0];
    unsigned int t1 = (s & 1) ? a.w[0] : a.w[1];
    unsigned int t2 = (s & 1) ? a.w[3] : a.w[2];
    unsigned int t3 = (s & 1) ? a.w[2] : a.w[3];
    unsigned int u0 = (s & 2) ? t2 : t0;
    unsigned int u1 = (s & 2) ? t3 : t1;
    unsigned int u2 = (s & 2) ? t0 : t2;
    unsigned int u3 = (s & 2) ? t1 : t3;
    if (jx & 1) {
        u0 = (u0 >> 16) | (u0 << 16);
        u1 = (u1 >> 16) | (u1 << 16);
        u2 = (u2 >> 16) | (u2 << 16);
        u3 = (u3 >> 16) | (u3 << 16);
    }
    b.w[0] = u0 ^ m0; b.w[1] = u1 ^ m1; b.w[2] = u2 ^ m2; b.w[3] = u3 ^ m3;
    return b.v8;
}

// ================= GEMM: A direct-to-register (NO A LDS), B-only LDS ring4 =================
// Block = one k x 128 b-rows. BM=128 BN=256 BK=64, 8 waves (2Mx4N), wave 64x64.
// A-operand: each lane loads its 8 A-octets (2 mt-rows x 4 k-slots, 16B) straight
//   from xb2[kt][row][128B]; octet permute o^kq folded into the LOAD ADDRESS;
//   jx-shuffle + sign via shuffle_sign in-register (equiv to R11 A-path, verified).
//   Ping-pong reg sets (E/O), prefetch distance 2 (tile T loads A(T+2) into set T&1
//   AFTER consuming A(T) from it).
// B-operand: unchanged — wb2 contiguous chunks via global_load_lds, subtile-major
//   LDS, ring4 x 32KB = 128KB total LDS (A LDS eliminated -> reads 128->64KB/tile).
// vm ledger (12 ops/tile: A 8 + B 4): entry pending {B(T+1) 4, A(T+1) 8, B(T+2) 4};
//   VMC(4) at entry retires B(T+1)+A(T+1). LGKM(4)->MFG0, LGKM(0)->MFG1. 1 bar/tile.

__global__ __launch_bounds__(512, 1) void gemm_ko32_kernel(const unsigned short* __restrict__ xb2,
                                                           const unsigned short* __restrict__ wb2,
                                                           float* __restrict__ Cws) {
    __shared__ char lds[131072];   // B ring4 x 32KB

    const int tid  = threadIdx.x;
    const int lane = tid & 63;
    const int wid  = tid >> 6;          // 0..7
    const int wr   = wid >> 2;          // 0..1
    const int wc   = wid & 3;           // 0..3
    const int l31  = lane & 31;
    const int l5   = lane >> 5;

    const int  kblk = blockIdx.x;
    const long row0 = (long)blockIdx.y * 128;
    const int  jx   = kblk & 7;
    const int  kq   = (kblk >> 3) & 3;

    // ---- A direct-load constants: per lane, rows (mt) and 4 source-octet offsets
    const char* aX = (const char*)xb2;
    const long rOff0 = (row0 + wr * 64 + l31) * 128;        // mt=0 row chunk
    const long rOff1 = rOff0 + 32 * 128;                    // mt=1
    // dest octet s = ks*2 + l5; source octet = s ^ kq (kq < 4, bit2 untouched)
    const int o0 = (((0 * 2 + l5) ^ kq) & 7) * 16;
    const int o1 = (((1 * 2 + l5) ^ kq) & 7) * 16;
    const int o2 = (((2 * 2 + l5) ^ kq) & 7) * 16;
    const int o3 = (((3 * 2 + l5) ^ kq) & 7) * 16;

    // ---- sign masks: two sets per lane — M for dest blade-octet q=l5, N for q=l5+2
    unsigned int M0, M1, M2, M3, N0, N1, N2, N3;
    {
        unsigned int mw[2][4];
#pragma unroll
        for (int u = 0; u < 2; ++u) {
            int q = l5 + u * 2;
#pragma unroll
            for (int w_ = 0; w_ < 4; ++w_) {
                unsigned int m_ = 0;
#pragma unroll
                for (int e2 = 0; e2 < 2; ++e2) {
                    int m = 8 * q + 2 * w_ + e2;
                    if (gp_sign(m, m ^ kblk) < 0.0f) m_ |= 0x8000u << (16 * e2);
                }
                mw[u][w_] = m_;
            }
        }
        M0 = mw[0][0]; M1 = mw[0][1]; M2 = mw[0][2]; M3 = mw[0][3];
        N0 = mw[1][0]; N1 = mw[1][1]; N2 = mw[1][2]; N3 = mw[1][3];
    }

    // ---- B staging: contiguous chunks from wb2 (identity perm both sides)
    const int  tid16 = tid * 16;
    const char* bSrc = (const char*)wb2 + tid16;

    // ---- B fragment-read bases (subtile-major, unchanged)
    const int bLp = wc * 8192;              // panel base (nt adds 4096)
    const int bC0 = (0 + l5) * 512 + l31 * 16;
    const int bC1 = (2 + l5) * 512 + l31 * 16;
    const int bC2 = (4 + l5) * 512 + l31 * 16;
    const int bC3 = (6 + l5) * 512 + l31 * 16;

#define B_STAGE(br, tb) { \
    _Pragma("unroll") for (int n = 0; n < 4; ++n) \
        gload_lds16(bSrc + (tb) + n * 8192, \
                    lds + (br) * 32768 + n * 8192 + tid16); }
// A loads: set S gets tile kt's 8 octets (dest slots ks*2+l5, source-octet-permuted)
#define A_LOAD(S, kt) { \
    const char* ab_ = aX + (long)(kt) * 131072; \
    S##00 = *(const bf16x8*)(ab_ + rOff0 + o0); \
    S##01 = *(const bf16x8*)(ab_ + rOff0 + o1); \
    S##02 = *(const bf16x8*)(ab_ + rOff0 + o2); \
    S##03 = *(const bf16x8*)(ab_ + rOff0 + o3); \
    S##10 = *(const bf16x8*)(ab_ + rOff1 + o0); \
    S##11 = *(const bf16x8*)(ab_ + rOff1 + o1); \
    S##12 = *(const bf16x8*)(ab_ + rOff1 + o2); \
    S##13 = *(const bf16x8*)(ab_ + rOff1 + o3); }
// shuffle+sign: frag f_mt_ks from set S; masks: ks even -> M, ks odd -> N
#define A_SHUF(S) { \
    f00 = shuffle_sign(S##00, jx, M0, M1, M2, M3); \
    f01 = shuffle_sign(S##01, jx, N0, N1, N2, N3); \
    f02 = shuffle_sign(S##02, jx, M0, M1, M2, M3); \
    f03 = shuffle_sign(S##03, jx, N0, N1, N2, N3); \
    f10 = shuffle_sign(S##10, jx, M0, M1, M2, M3); \
    f11 = shuffle_sign(S##11, jx, N0, N1, N2, N3); \
    f12 = shuffle_sign(S##12, jx, M0, M1, M2, M3); \
    f13 = shuffle_sign(S##13, jx, N0, N1, N2, N3); }
#define READ_B0(br) { \
    bG0[0][0] = *(const bf16x8*)(lds + (br)*32768 + bLp + 0*4096 + bC0); \
    bG0[0][1] = *(const bf16x8*)(lds + (br)*32768 + bLp + 0*4096 + bC1); \
    bG0[1][0] = *(const bf16x8*)(lds + (br)*32768 + bLp + 1*4096 + bC0); \
    bG0[1][1] = *(const bf16x8*)(lds + (br)*32768 + bLp + 1*4096 + bC1); }
#define READ_B1(br) { \
    bG1[0][0] = *(const bf16x8*)(lds + (br)*32768 + bLp + 0*4096 + bC2); \
    bG1[0][1] = *(const bf16x8*)(lds + (br)*32768 + bLp + 0*4096 + bC3); \
    bG1[1][0] = *(const bf16x8*)(lds + (br)*32768 + bLp + 1*4096 + bC2); \
    bG1[1][1] = *(const bf16x8*)(lds + (br)*32768 + bLp + 1*4096 + bC3); }
#define MFG0() { \
    _Pragma("unroll") for (int nt = 0; nt < 2; ++nt) { \
        acc[0][nt] = __builtin_amdgcn_mfma_f32_32x32x16_bf16(f00, bG0[nt][0], acc[0][nt], 0, 0, 0); \
        acc[1][nt] = __builtin_amdgcn_mfma_f32_32x32x16_bf16(f10, bG0[nt][0], acc[1][nt], 0, 0, 0); \
        acc[0][nt] = __builtin_amdgcn_mfma_f32_32x32x16_bf16(f01, bG0[nt][1], acc[0][nt], 0, 0, 0); \
        acc[1][nt] = __builtin_amdgcn_mfma_f32_32x32x16_bf16(f11, bG0[nt][1], acc[1][nt], 0, 0, 0); } }
#define MFG1() { \
    _Pragma("unroll") for (int nt = 0; nt < 2; ++nt) { \
        acc[0][nt] = __builtin_amdgcn_mfma_f32_32x32x16_bf16(f02, bG1[nt][0], acc[0][nt], 0, 0, 0); \
        acc[1][nt] = __builtin_amdgcn_mfma_f32_32x32x16_bf16(f12, bG1[nt][0], acc[1][nt], 0, 0, 0); \
        acc[0][nt] = __builtin_amdgcn_mfma_f32_32x32x16_bf16(f03, bG1[nt][1], acc[0][nt], 0, 0, 0); \
        acc[1][nt] = __builtin_amdgcn_mfma_f32_32x32x16_bf16(f13, bG1[nt][1], acc[1][nt], 0, 0, 0); } }

    f32x16 acc[2][2];
#pragma unroll
    for (int mt = 0; mt < 2; ++mt)
#pragma unroll
        for (int nt = 0; nt < 2; ++nt) acc[mt][nt] = (f32x16)0.0f;

    bf16x8 aE00, aE01, aE02, aE03, aE10, aE11, aE12, aE13;
    bf16x8 aO00, aO01, aO02, aO03, aO10, aO11, aO12, aO13;
    bf16x8 f00, f01, f02, f03, f10, f11, f12, f13;
    bf16x8 bG0[2][2], bG1[2][2];

    // ---- prologue: A(0)->E, A(1)->O; B(0..2) staged. Pending after: B1,A1,B2 = 16.
    A_LOAD(aE, 0);          // A(0)  [8]
    SCHED0();
    B_STAGE(0, 0);          // B(0)  [12]
    B_STAGE(1, 32768);      // B(1)  [16]
    SCHED0();
    A_LOAD(aO, 1);          // A(1)  [24]
    SCHED0();
    B_STAGE(2, 65536);      // B(2)  [28]
    SCHED0();
    VMC(16);                // retire A(0)+B(0) -> A(0) & B(0) ready
    BAR();

    // body: tile T: consume A(T) from set T&1, reload same set with A(T+2).
#define TILE32(BR, BRS, S, Texp) { \
    const int T_ = (Texp); \
    READ_B0(BR); \
    READ_B1(BR); \
    VMC(4);                /* retire B(T+1)+A(T+1) */ \
    A_SHUF(S); \
    SCHED0(); \
    A_LOAD(S, (T_ + 2) & 127);                  /* 8 vm */ \
    SCHED0(); \
    B_STAGE(BRS, (long)((T_ + 3) & 127) << 15); /* 4 vm */ \
    SCHED0(); \
    LGKM(4); MFG0(); \
    LGKM(0); MFG1(); \
    BAR(); }

    for (int t = 0; t < 32; ++t) {
        const int T4 = t * 4;
        TILE32(0, 3, aE, T4);
        TILE32(1, 0, aO, T4 + 1);
        TILE32(2, 1, aE, T4 + 2);
        TILE32(3, 2, aO, T4 + 3);
    }

    // ---- epilogue: 32x32 C/D layout col=lane&31, row=(r&3)+8*(r>>2)+4*l5 (m74/m101)
#pragma unroll
    for (int mt = 0; mt < 2; ++mt)
#pragma unroll
        for (int nt = 0; nt < 2; ++nt) {
            long c = (long)kblk * 256 + wc * 64 + nt * 32 + l31;
#pragma unroll
            for (int r = 0; r < 16; ++r) {
                int  rl = (r & 3) + 8 * (r >> 2) + 4 * l5;
                long rb = row0 + wr * 64 + mt * 32 + rl;
                Cws[rb * N_DIM + c] = acc[mt][nt][r];
            }
        }

#undef B_STAGE
#undef A_LOAD
#undef A_SHUF
#undef READ_B0
#undef READ_B1
#undef MFG0
#undef MFG1
#undef TILE32
}

// ---------- transpose: out[b][o*32+k] = Cws[b][k*256+o] ----------
__global__ __launch_bounds__(256) void transpose_kernel(const float* __restrict__ Cws,
                                                        float* __restrict__ out) {
    __shared__ float t[32 * 260];
    const int tid = threadIdx.x;
    const long b  = blockIdx.x;
    const float4* src = (const float4*)(Cws + b * N_DIM);
    float4*       dst = (float4*)(out + b * N_DIM);
#pragma unroll
    for (int r = 0; r < 8; ++r) {
        int f = tid + r * 256;
        float4 v = src[f];
        int k  = f >> 6;
        int c4 = (f & 63) * 4;
        *(float4*)&t[k * 260 + c4] = v;
    }
    __syncthreads();
#pragma unroll
    for (int r = 0; r < 8; ++r) {
        int g  = tid + r * 256;
        int o  = g >> 3;
        int k0 = (g & 7) * 4;
        float4 v;
        v.x = t[(k0 + 0) * 260 + o];
        v.y = t[(k0 + 1) * 260 + o];
        v.z = t[(k0 + 2) * 260 + o];
        v.w = t[(k0 + 3) * 260 + o];
        dst[g] = v;
    }
}

// ---------- fallback (ws tiny): direct fp32, correct but slow ----------
__global__ __launch_bounds__(256) void fallback_gp_kernel(const float* __restrict__ x,
                                                          const float* __restrict__ w,
                                                          float* __restrict__ out) {
    __shared__ float xs[IN_DIM * 32];
    __shared__ float tab[1024];
    int tid = threadIdx.x;
    for (int idx = tid; idx < 1024; idx += 256) {
        int m = idx >> 5, k = idx & 31;
        tab[idx] = gp_sign(m, m ^ k);
    }
    int b = blockIdx.x;
    const float4* xrow = (const float4*)(x + (long)b * K_DIM);
    float4* xs4 = (float4*)xs;
    for (int idx = tid; idx < 2048; idx += 256) xs4[idx] = xrow[idx];
    __syncthreads();

    int wid = tid >> 6, lane = tid & 63;
    int o = blockIdx.y * 8 + wid;
    int k = lane & 31, half = lane >> 5;
    float acc = 0.f;
    const float* wrow = w + (long)o * K_DIM + half * 4096;
    for (int i = 0; i < 128; ++i) {
        int ib = (half * 128 + i) * 32;
#pragma unroll
        for (int m = 0; m < 32; ++m) {
            acc += xs[ib + (m ^ k)] * tab[m * 32 + k] * wrow[i * 32 + m];
        }
    }
    acc += __shfl_down(acc, 32);
    if (half == 0) out[((long)b * OUT_DIM + o) * 32 + k] = acc;
}

// ---------- launch ----------
extern "C" void kernel_launch(void* const* d_in, const int* in_sizes, int n_in,
                              void* d_out, int out_size, void* d_ws, size_t ws_size,
                              hipStream_t stream) {
    const float* x = (const float*)d_in[0];
    const float* w = (const float*)d_in[1];
    float* out = (float*)d_out;

    const size_t xb_bytes  = (size_t)B_DIM * K_DIM * 2;          // 16 MiB
    const size_t wb_bytes  = (size_t)OUT_DIM * IN_DIM * 32 * 2;  // 4.2 MB
    const size_t cw_bytes  = (size_t)B_DIM * N_DIM * 4;          // 32 MiB
    const size_t need = xb_bytes + wb_bytes + cw_bytes;          // ~54 MB

    if (ws_size >= need) {
        unsigned short* xbp = (unsigned short*)d_ws;
        unsigned short* wbp = (unsigned short*)((char*)d_ws + xb_bytes);
        float*          cws = (float*)((char*)d_ws + xb_bytes + wb_bytes);

        cast_x2_kernel<<<dim3(4096), dim3(256), 0, stream>>>(x, xbp);
        cast_w_perm_kernel<<<dim3(1024), dim3(256), 0, stream>>>(w, wbp);
        gemm_ko32_kernel<<<dim3(32, 8), dim3(512), 0, stream>>>(xbp, wbp, cws);
        transpose_kernel<<<dim3(B_DIM), dim3(256), 0, stream>>>(cws, out);
    } else {
        fallback_gp_kernel<<<dim3(B_DIM, OUT_DIM / 8), dim3(256), 0, stream>>>(x, w, out);
    }
}

// Round 13
// 189.896 us; speedup vs baseline: 1.5315x; 1.5315x over previous
//
#include <hip/hip_runtime.h>

typedef __attribute__((ext_vector_type(8))) short bf16x8;
typedef __attribute__((ext_vector_type(16))) float f32x16;
typedef __attribute__((ext_vector_type(8))) unsigned short ushort8;

#define N_BLADES 32
#define B_DIM 1024
#define IN_DIM 256
#define OUT_DIM 256
#define K_DIM (IN_DIM * N_BLADES)   // 8192
#define N_DIM (OUT_DIM * N_BLADES)  // 8192

// ---------- helpers ----------

__device__ __forceinline__ unsigned short f2bf(float f) {
    unsigned int u = __float_as_uint(f);
    u = (u + 0x7fff + ((u >> 16) & 1)) >> 16;   // RNE
    return (unsigned short)u;
}

__device__ __forceinline__ float gp_sign(int a, int b) {
    int swaps = 0;
#pragma unroll
    for (int i = 0; i < 5; ++i) {
        int mask = (~((1 << (i + 1)) - 1)) & 31;
        swaps += ((b >> i) & 1) * __popc(a & mask);
    }
    float s = (swaps & 1) ? -1.0f : 1.0f;
    if (a & b & 16) s = -s;
    return s;
}

__device__ __forceinline__ void gload_lds16(const void* g, void* l) {
    __builtin_amdgcn_global_load_lds(
        (const __attribute__((address_space(1))) unsigned int*)g,
        (__attribute__((address_space(3))) unsigned int*)l, 16, 0, 0);
}

#define FENCE() asm volatile("" ::: "memory")
#define BAR()    { FENCE(); __builtin_amdgcn_s_barrier(); FENCE(); }
#define SCHED0() __builtin_amdgcn_sched_barrier(0)
#define LGKM(n)  { asm volatile("s_waitcnt lgkmcnt(" #n ")" ::: "memory"); }
#define VMC(n)   { asm volatile("s_waitcnt vmcnt(" #n ")" ::: "memory"); }

// ---------- prep: cast x fp32 -> bf16 into TRANSPOSED layout xb2[kt][b][128B] ----------
__global__ __launch_bounds__(256) void cast_x2_kernel(const float* __restrict__ x,
                                                      unsigned short* __restrict__ xb2) {
    int t = blockIdx.x * 256 + threadIdx.x;    // 1,048,576 octets
    int o  = t & 7;
    int b  = (t >> 3) & 1023;
    int kt = t >> 13;
    const float4* src = (const float4*)(x + (long)b * K_DIM + kt * 64 + o * 8);
    float4 a = src[0], c = src[1];
    ushort8 pk;
    pk[0] = f2bf(a.x); pk[1] = f2bf(a.y); pk[2] = f2bf(a.z); pk[3] = f2bf(a.w);
    pk[4] = f2bf(c.x); pk[5] = f2bf(c.y); pk[6] = f2bf(c.z); pk[7] = f2bf(c.w);
    *(ushort8*)(xb2 + ((size_t)kt * 8192 + b * 8 + o) * 8) = pk;
}

// ---------- prep: cast + permute w into staged order (known-good) ----------
__global__ __launch_bounds__(256) void cast_w_perm_kernel(const float* __restrict__ w,
                                                          unsigned short* __restrict__ wb2) {
    int t = blockIdx.x * 256 + threadIdx.x;    // 262144 octets
    int o31   = t & 31;
    int c16   = (t >> 5) & 7;
    int panel = (t >> 8) & 7;
    int kt    = t >> 11;
    int o  = panel * 32 + o31;
    int k0 = kt * 64 + c16 * 8;
    const float4* src = (const float4*)(w + (long)o * K_DIM + k0);
    float4 a = src[0], b = src[1];
    ushort8 pk;
    pk[0] = f2bf(a.x); pk[1] = f2bf(a.y); pk[2] = f2bf(a.z); pk[3] = f2bf(a.w);
    pk[4] = f2bf(b.x); pk[5] = f2bf(b.y); pk[6] = f2bf(b.z); pk[7] = f2bf(b.w);
    *(ushort8*)(wb2 + (size_t)t * 8) = pk;
}

// ---------- uniform-j XOR shuffle + sign mask on a bf16 octet (verified) ----------
__device__ __forceinline__ bf16x8 shuffle_sign(bf16x8 v, int jx,
                                               unsigned int m0, unsigned int m1,
                                               unsigned int m2, unsigned int m3) {
    union { bf16x8 v8; unsigned int w[4]; } a, b;
    a.v8 = v;
    int s = jx >> 1;
    unsigned int t0 = (s & 1) ? a.w[1] : a.w[0];
    unsigned int t1 = (s & 1) ? a.w[0] : a.w[1];
    unsigned int t2 = (s & 1) ? a.w[3] : a.w[2];
    unsigned int t3 = (s & 1) ? a.w[2] : a.w[3];
    unsigned int u0 = (s & 2) ? t2 : t0;
    unsigned int u1 = (s & 2) ? t3 : t1;
    unsigned int u2 = (s & 2) ? t0 : t2;
    unsigned int u3 = (s & 2) ? t1 : t3;
    if (jx & 1) {
        u0 = (u0 >> 16) | (u0 << 16);
        u1 = (u1 >> 16) | (u1 << 16);
        u2 = (u2 >> 16) | (u2 << 16);
        u3 = (u3 >> 16) | (u3 << 16);
    }
    b.w[0] = u0 ^ m0; b.w[1] = u1 ^ m1; b.w[2] = u2 ^ m2; b.w[3] = u3 ^ m3;
    return b.v8;
}

// ================= GEMM: BM=256 BN=256 BK=64, wave tile 128x64, split-K z=2 =================
// grid (32 k, 4 mb, 2 z). 512 thr, 8 waves (2 wr x 4 wc). 64 K-tiles per block.
// LDS: A ring2 x 32KB @0; B ring3 x 32KB @65536 = 160KB. Subtile-major layout both:
//   addr = panel(row>>5)*4096 + slot*512 + (row&31)*16  (conflict-free, R9-verified).
// A staged: regs from xb2 (WAVE-CONTIGUOUS 4KB: 2 thr/row, octet perm s^kq in src addr)
//   -> shuffle_sign(jx, mask[s&3]) -> ds_write (2-way = free).  B: wb2 DMA (identity).
// Ledger: tile J issues [A(J+2) 4vm, B(J+2)->buf (J+2)%3 4vm]. Entry VMC(4) retires
//   B(J) + A(J+1) (both >=1 tile old), leaves B(J+1). 32 MFMA/wave/tile in 2 clusters:
//   issue 4w+16r, LGKM(4)->MFG01, read A23, LGKM(0)->MFG23. 1 barrier/tile.

__global__ __launch_bounds__(512, 1) void gemm_big_kernel(const unsigned short* __restrict__ xb2,
                                                          const unsigned short* __restrict__ wb2,
                                                          float* __restrict__ C0,
                                                          float* __restrict__ C1) {
    __shared__ char lds[163840];

    const int tid  = threadIdx.x;
    const int lane = tid & 63;
    const int wid  = tid >> 6;
    const int wr   = wid >> 2;          // 0..1
    const int wc   = wid & 3;           // 0..3
    const int l31  = lane & 31;
    const int l5   = lane >> 5;

    const int  kblk = blockIdx.x;
    const int  mb   = blockIdx.y;
    const int  z    = blockIdx.z;
    float* __restrict__ C = z ? C1 : C0;
    const int  kt0  = z * 64;
    const int  jx   = kblk & 7;
    const int  kq   = (kblk >> 3) & 3;

    // ---- A staging: 2 threads/row; row rA=tid>>1, slot group g=tid&1 (slots 4g..4g+3)
    const int rA = tid >> 1;
    const int g4 = (tid & 1) * 4;
    const char* xbB = (const char*)xb2 + (long)(mb * 256 + rA) * 128;
    const int o0 = ((g4 + 0) ^ kq) * 16;
    const int o1 = ((g4 + 1) ^ kq) * 16;
    const int o2 = ((g4 + 2) ^ kq) * 16;
    const int o3 = ((g4 + 3) ^ kq) * 16;
    const int adw_base = (rA >> 5) * 4096 + (rA & 31) * 16;
    const int adw0 = adw_base + (g4 + 0) * 512;
    const int adw1 = adw_base + (g4 + 1) * 512;
    const int adw2 = adw_base + (g4 + 2) * 512;
    const int adw3 = adw_base + (g4 + 3) * 512;

    // sign masks mk[q][word], q = slot&3 = i (block-uniform -> SGPR)
    unsigned int mk[4][4];
#pragma unroll
    for (int q = 0; q < 4; ++q)
#pragma unroll
        for (int w_ = 0; w_ < 4; ++w_) {
            unsigned int m_ = 0;
#pragma unroll
            for (int e2 = 0; e2 < 2; ++e2) {
                int m = 8 * q + 2 * w_ + e2;
                if (gp_sign(m, m ^ kblk) < 0.0f) m_ |= 0x8000u << (16 * e2);
            }
            mk[q][w_] = m_;
        }

    // ---- B staging + fragment bases
    const int  tid16 = tid * 16;
    const char* bSrc = (const char*)wb2 + tid16;
    const int aPan = wr * 16384;            // + mt*4096
    const int bPan = 65536 + wc * 8192;     // + br*32768 + nt*4096
    const int cc0 = (0 + l5) * 512 + l31 * 16;
    const int cc1 = (2 + l5) * 512 + l31 * 16;
    const int cc2 = (4 + l5) * 512 + l31 * 16;
    const int cc3 = (6 + l5) * 512 + l31 * 16;

#define B_STAGE(br, ktv) { \
    const long tb_ = (long)(ktv) * 32768; \
    _Pragma("unroll") for (int n = 0; n < 4; ++n) \
        gload_lds16(bSrc + tb_ + n * 8192, lds + 65536 + (br) * 32768 + n * 8192 + tid16); }
#define A_LOAD(S, ktv) { \
    const char* p_ = xbB + (long)(ktv) * 131072; \
    S##0 = *(const bf16x8*)(p_ + o0); \
    S##1 = *(const bf16x8*)(p_ + o1); \
    S##2 = *(const bf16x8*)(p_ + o2); \
    S##3 = *(const bf16x8*)(p_ + o3); }
#define A_SHUF_WRITE(S, ab) { \
    bf16x8 f0_ = shuffle_sign(S##0, jx, mk[0][0], mk[0][1], mk[0][2], mk[0][3]); \
    bf16x8 f1_ = shuffle_sign(S##1, jx, mk[1][0], mk[1][1], mk[1][2], mk[1][3]); \
    bf16x8 f2_ = shuffle_sign(S##2, jx, mk[2][0], mk[2][1], mk[2][2], mk[2][3]); \
    bf16x8 f3_ = shuffle_sign(S##3, jx, mk[3][0], mk[3][1], mk[3][2], mk[3][3]); \
    *(bf16x8*)(lds + (ab) * 32768 + adw0) = f0_; \
    *(bf16x8*)(lds + (ab) * 32768 + adw1) = f1_; \
    *(bf16x8*)(lds + (ab) * 32768 + adw2) = f2_; \
    *(bf16x8*)(lds + (ab) * 32768 + adw3) = f3_; }
#define READ_B01(br) { \
    _Pragma("unroll") for (int nt = 0; nt < 2; ++nt) { \
        bF[nt][0] = *(const bf16x8*)(lds + bPan + (br)*32768 + nt*4096 + cc0); \
        bF[nt][1] = *(const bf16x8*)(lds + bPan + (br)*32768 + nt*4096 + cc1); } }
#define READ_B23(br) { \
    _Pragma("unroll") for (int nt = 0; nt < 2; ++nt) { \
        bF[nt][2] = *(const bf16x8*)(lds + bPan + (br)*32768 + nt*4096 + cc2); \
        bF[nt][3] = *(const bf16x8*)(lds + bPan + (br)*32768 + nt*4096 + cc3); } }
#define READ_A01(ab) { \
    _Pragma("unroll") for (int mt = 0; mt < 4; ++mt) { \
        aF[mt][0] = *(const bf16x8*)(lds + (ab)*32768 + aPan + mt*4096 + cc0); \
        aF[mt][1] = *(const bf16x8*)(lds + (ab)*32768 + aPan + mt*4096 + cc1); } }
#define READ_A23(ab) { \
    _Pragma("unroll") for (int mt = 0; mt < 4; ++mt) { \
        aF[mt][0] = *(const bf16x8*)(lds + (ab)*32768 + aPan + mt*4096 + cc2); \
        aF[mt][1] = *(const bf16x8*)(lds + (ab)*32768 + aPan + mt*4096 + cc3); } }
#define MFG01() \
    _Pragma("unroll") for (int s = 0; s < 2; ++s) \
    _Pragma("unroll") for (int mt = 0; mt < 4; ++mt) \
    _Pragma("unroll") for (int nt = 0; nt < 2; ++nt) \
        acc[mt][nt] = __builtin_amdgcn_mfma_f32_32x32x16_bf16(aF[mt][s], bF[nt][s], acc[mt][nt], 0, 0, 0);
#define MFG23() \
    _Pragma("unroll") for (int s = 0; s < 2; ++s) \
    _Pragma("unroll") for (int mt = 0; mt < 4; ++mt) \
    _Pragma("unroll") for (int nt = 0; nt < 2; ++nt) \
        acc[mt][nt] = __builtin_amdgcn_mfma_f32_32x32x16_bf16(aF[mt][s], bF[nt][2 + s], acc[mt][nt], 0, 0, 0);

    f32x16 acc[4][2];
#pragma unroll
    for (int mt = 0; mt < 4; ++mt)
#pragma unroll
        for (int nt = 0; nt < 2; ++nt) acc[mt][nt] = (f32x16)0.0f;

    bf16x8 aE0, aE1, aE2, aE3, aO0, aO1, aO2, aO3;
    bf16x8 aF[4][2], bF[2][4];

    // ---- prologue: A(0)->abuf0; queue at tile0 entry = [B(0), A(1), B(1)]
    A_LOAD(aE, kt0);
    SCHED0();
    VMC(0);
    A_SHUF_WRITE(aE, 0);
    SCHED0();
    B_STAGE(0, kt0);            // B(0) [4]
    SCHED0();
    A_LOAD(aO, kt0 + 1);        // A(1) [8]
    SCHED0();
    B_STAGE(1, kt0 + 1);        // B(1) [12]
    SCHED0();
    LGKM(0);
    BAR();

    // tile position p = J%6: ABR=p&1 ABW=(p+1)&1 SW=set[(p+1)&1] SL=set[p&1]
    //                        BRR=p%3 BRS=(p+2)%3
#define TILE(Jv, ABR, ABW, SW, SL, BRR, BRS) { \
    const int ktp = (kt0 + (Jv) + 2) & 127; \
    VMC(4);                    /* B(J), A(J+1) retired; B(J+1) stays */ \
    A_SHUF_WRITE(SW, ABW);     /* 4 ds_w */ \
    SCHED0(); \
    READ_B01(BRR); \
    READ_A01(ABR); \
    READ_B23(BRR);             /* lgkm out: 20 */ \
    SCHED0(); \
    A_LOAD(SL, ktp);           /* 4 vm */ \
    SCHED0(); \
    B_STAGE(BRS, ktp);         /* 4 vm */ \
    SCHED0(); \
    LGKM(4);                   /* writes+B01+A01 done; B23 pending */ \
    MFG01(); \
    READ_A23(ABR); \
    SCHED0(); \
    LGKM(0); \
    MFG23(); \
    BAR(); }

    for (int t = 0; t < 60; t += 6) {
        TILE(t + 0, 0, 1, aO, aE, 0, 2);
        TILE(t + 1, 1, 0, aE, aO, 1, 0);
        TILE(t + 2, 0, 1, aO, aE, 2, 1);
        TILE(t + 3, 1, 0, aE, aO, 0, 2);
        TILE(t + 4, 0, 1, aO, aE, 1, 0);
        TILE(t + 5, 1, 0, aE, aO, 2, 1);
    }
    TILE(60, 0, 1, aO, aE, 0, 2);
    TILE(61, 1, 0, aE, aO, 1, 0);
    TILE(62, 0, 1, aO, aE, 2, 1);
    TILE(63, 1, 0, aE, aO, 0, 2);

    // ---- epilogue: 32x32 C/D layout col=lane&31, row=(r&3)+8*(r>>2)+4*l5
#pragma unroll
    for (int mt = 0; mt < 4; ++mt)
#pragma unroll
        for (int nt = 0; nt < 2; ++nt) {
            long c = (long)kblk * 256 + wc * 64 + nt * 32 + l31;
#pragma unroll
            for (int r = 0; r < 16; ++r) {
                int  rl = (r & 3) + 8 * (r >> 2) + 4 * l5;
                long rb = (long)mb * 256 + wr * 128 + mt * 32 + rl;
                C[rb * N_DIM + c] = acc[mt][nt][r];
            }
        }

#undef B_STAGE
#undef A_LOAD
#undef A_SHUF_WRITE
#undef READ_B01
#undef READ_B23
#undef READ_A01
#undef READ_A23
#undef MFG01
#undef MFG23
#undef TILE
}

// ---------- fused transpose + split-K reduce: out[b][o*32+k] = C0+C1 at [b][k*256+o] ----------
__global__ __launch_bounds__(256) void transpose_add_kernel(const float* __restrict__ C0,
                                                            const float* __restrict__ C1,
                                                            float* __restrict__ out) {
    __shared__ float t[32 * 260];
    const int tid = threadIdx.x;
    const long b  = blockIdx.x;
    const float4* s0 = (const float4*)(C0 + b * N_DIM);
    const float4* s1 = (const float4*)(C1 + b * N_DIM);
    float4*       dst = (float4*)(out + b * N_DIM);
#pragma unroll
    for (int r = 0; r < 8; ++r) {
        int f = tid + r * 256;
        float4 v = s0[f], u = s1[f];
        v.x += u.x; v.y += u.y; v.z += u.z; v.w += u.w;
        int k  = f >> 6;
        int c4 = (f & 63) * 4;
        *(float4*)&t[k * 260 + c4] = v;
    }
    __syncthreads();
#pragma unroll
    for (int r = 0; r < 8; ++r) {
        int g  = tid + r * 256;
        int o  = g >> 3;
        int k0 = (g & 7) * 4;
        float4 v;
        v.x = t[(k0 + 0) * 260 + o];
        v.y = t[(k0 + 1) * 260 + o];
        v.z = t[(k0 + 2) * 260 + o];
        v.w = t[(k0 + 3) * 260 + o];
        dst[g] = v;
    }
}

// ---------- fallback (ws tiny): direct fp32, correct but slow ----------
__global__ __launch_bounds__(256) void fallback_gp_kernel(const float* __restrict__ x,
                                                          const float* __restrict__ w,
                                                          float* __restrict__ out) {
    __shared__ float xs[IN_DIM * 32];
    __shared__ float tab[1024];
    int tid = threadIdx.x;
    for (int idx = tid; idx < 1024; idx += 256) {
        int m = idx >> 5, k = idx & 31;
        tab[idx] = gp_sign(m, m ^ k);
    }
    int b = blockIdx.x;
    const float4* xrow = (const float4*)(x + (long)b * K_DIM);
    float4* xs4 = (float4*)xs;
    for (int idx = tid; idx < 2048; idx += 256) xs4[idx] = xrow[idx];
    __syncthreads();

    int wid = tid >> 6, lane = tid & 63;
    int o = blockIdx.y * 8 + wid;
    int k = lane & 31, half = lane >> 5;
    float acc = 0.f;
    const float* wrow = w + (long)o * K_DIM + half * 4096;
    for (int i = 0; i < 128; ++i) {
        int ib = (half * 128 + i) * 32;
#pragma unroll
        for (int m = 0; m < 32; ++m) {
            acc += xs[ib + (m ^ k)] * tab[m * 32 + k] * wrow[i * 32 + m];
        }
    }
    acc += __shfl_down(acc, 32);
    if (half == 0) out[((long)b * OUT_DIM + o) * 32 + k] = acc;
}

// ---------- launch ----------
extern "C" void kernel_launch(void* const* d_in, const int* in_sizes, int n_in,
                              void* d_out, int out_size, void* d_ws, size_t ws_size,
                              hipStream_t stream) {
    const float* x = (const float*)d_in[0];
    const float* w = (const float*)d_in[1];
    float* out = (float*)d_out;

    const size_t xb_bytes = (size_t)B_DIM * K_DIM * 2;           // 16 MiB
    const size_t wb_bytes = (size_t)OUT_DIM * IN_DIM * 32 * 2;   // 4.2 MB
    const size_t cw_bytes = (size_t)B_DIM * N_DIM * 4;           // 32 MiB
    const size_t need = xb_bytes + wb_bytes + 2 * cw_bytes;      // ~84 MB

    if (ws_size >= need) {
        unsigned short* xbp = (unsigned short*)d_ws;
        unsigned short* wbp = (unsigned short*)((char*)d_ws + xb_bytes);
        float* c0 = (float*)((char*)d_ws + xb_bytes + wb_bytes);
        float* c1 = (float*)((char*)d_ws + xb_bytes + wb_bytes + cw_bytes);

        cast_x2_kernel<<<dim3(4096), dim3(256), 0, stream>>>(x, xbp);
        cast_w_perm_kernel<<<dim3(1024), dim3(256), 0, stream>>>(w, wbp);
        gemm_big_kernel<<<dim3(32, 4, 2), dim3(512), 0, stream>>>(xbp, wbp, c0, c1);
        transpose_add_kernel<<<dim3(B_DIM), dim3(256), 0, stream>>>(c0, c1, out);
    } else {
        fallback_gp_kernel<<<dim3(B_DIM, OUT_DIM / 8), dim3(256), 0, stream>>>(x, w, out);
    }
}

// Round 14
// 157.767 us; speedup vs baseline: 1.8433x; 1.2036x over previous
//
#include <hip/hip_runtime.h>

typedef __attribute__((ext_vector_type(8))) short bf16x8;
typedef __attribute__((ext_vector_type(16))) float f32x16;
typedef __attribute__((ext_vector_type(8))) unsigned short ushort8;

#define N_BLADES 32
#define B_DIM 1024
#define IN_DIM 256
#define OUT_DIM 256
#define K_DIM (IN_DIM * N_BLADES)   // 8192
#define N_DIM (OUT_DIM * N_BLADES)  // 8192

// ---------- helpers ----------

__device__ __forceinline__ unsigned short f2bf(float f) {
    unsigned int u = __float_as_uint(f);
    u = (u + 0x7fff + ((u >> 16) & 1)) >> 16;   // RNE
    return (unsigned short)u;
}

__device__ __forceinline__ float gp_sign(int a, int b) {
    int swaps = 0;
#pragma unroll
    for (int i = 0; i < 5; ++i) {
        int mask = (~((1 << (i + 1)) - 1)) & 31;
        swaps += ((b >> i) & 1) * __popc(a & mask);
    }
    float s = (swaps & 1) ? -1.0f : 1.0f;
    if (a & b & 16) s = -s;
    return s;
}

__device__ __forceinline__ void gload_lds16(const void* g, void* l) {
    __builtin_amdgcn_global_load_lds(
        (const __attribute__((address_space(1))) unsigned int*)g,
        (__attribute__((address_space(3))) unsigned int*)l, 16, 0, 0);
}

#define FENCE() asm volatile("" ::: "memory")
#define BAR()    { FENCE(); __builtin_amdgcn_s_barrier(); FENCE(); }
#define SCHED0() __builtin_amdgcn_sched_barrier(0)
#define LGKM(n)  { asm volatile("s_waitcnt lgkmcnt(" #n ")" ::: "memory"); }
#define VMC(n)   { asm volatile("s_waitcnt vmcnt(" #n ")" ::: "memory"); }

// ---------- prep: cast x fp32 -> bf16 into TRANSPOSED layout xb2[kt][b][128B] ----------
__global__ __launch_bounds__(256) void cast_x2_kernel(const float* __restrict__ x,
                                                      unsigned short* __restrict__ xb2) {
    int t = blockIdx.x * 256 + threadIdx.x;    // 1,048,576 octets
    int o  = t & 7;
    int b  = (t >> 3) & 1023;
    int kt = t >> 13;
    const float4* src = (const float4*)(x + (long)b * K_DIM + kt * 64 + o * 8);
    float4 a = src[0], c = src[1];
    ushort8 pk;
    pk[0] = f2bf(a.x); pk[1] = f2bf(a.y); pk[2] = f2bf(a.z); pk[3] = f2bf(a.w);
    pk[4] = f2bf(c.x); pk[5] = f2bf(c.y); pk[6] = f2bf(c.z); pk[7] = f2bf(c.w);
    *(ushort8*)(xb2 + ((size_t)kt * 8192 + b * 8 + o) * 8) = pk;
}

// ---------- prep: cast + permute w into staged order (known-good) ----------
__global__ __launch_bounds__(256) void cast_w_perm_kernel(const float* __restrict__ w,
                                                          unsigned short* __restrict__ wb2) {
    int t = blockIdx.x * 256 + threadIdx.x;    // 262144 octets
    int o31   = t & 31;
    int c16   = (t >> 5) & 7;
    int panel = (t >> 8) & 7;
    int kt    = t >> 11;
    int o  = panel * 32 + o31;
    int k0 = kt * 64 + c16 * 8;
    const float4* src = (const float4*)(w + (long)o * K_DIM + k0);
    float4 a = src[0], b = src[1];
    ushort8 pk;
    pk[0] = f2bf(a.x); pk[1] = f2bf(a.y); pk[2] = f2bf(a.z); pk[3] = f2bf(a.w);
    pk[4] = f2bf(b.x); pk[5] = f2bf(b.y); pk[6] = f2bf(b.z); pk[7] = f2bf(b.w);
    *(ushort8*)(wb2 + (size_t)t * 8) = pk;
}

// ---------- uniform-j XOR shuffle + sign mask on a bf16 octet (verified) ----------
__device__ __forceinline__ bf16x8 shuffle_sign(bf16x8 v, int jx,
                                               unsigned int m0, unsigned int m1,
                                               unsigned int m2, unsigned int m3) {
    union { bf16x8 v8; unsigned int w[4]; } a, b;
    a.v8 = v;
    int s = jx >> 1;
    unsigned int t0 = (s & 1) ? a.w[1] : a.w[0];
    unsigned int t1 = (s & 1) ? a.w[0] : a.w[1];
    unsigned int t2 = (s & 1) ? a.w[3] : a.w[2];
    unsigned int t3 = (s & 1) ? a.w[2] : a.w[3];
    unsigned int u0 = (s & 2) ? t2 : t0;
    unsigned int u1 = (s & 2) ? t3 : t1;
    unsigned int u2 = (s & 2) ? t0 : t2;
    unsigned int u3 = (s & 2) ? t1 : t3;
    if (jx & 1) {
        u0 = (u0 >> 16) | (u0 << 16);
        u1 = (u1 >> 16) | (u1 << 16);
        u2 = (u2 >> 16) | (u2 << 16);
        u3 = (u3 >> 16) | (u3 << 16);
    }
    b.w[0] = u0 ^ m0; b.w[1] = u1 ^ m1; b.w[2] = u2 ^ m2; b.w[3] = u3 ^ m3;
    return b.v8;
}

// ================= GEMM: BM=256 BN=256 BK=64, wave tile 128x64, split-K z=2 =================
// R13 geometry, two fixes:
//  (1) amdgpu_waves_per_eu(2,2): LDS already caps at 1 block/CU = 2 waves/EU; pin it
//      so the VGPR budget is 256 -> no spill (R13: VGPR=128, acc spilled to scratch,
//      WRITE_SIZE 169MB). Register diet: single A staging set S[4]; A frags X[4]/Y[4]
//      reused across slot-pairs; bF[2][4]. Live ~210 VGPR.
//  (2) A LDS map pos' = (row&31) ^ (slot&4): per ds_write instr the 8 consecutive
//      lanes (rows 4r..4r+3 x g4{0,4}) hit 8 distinct pos'&7 -> conflict-free
//      (R13: 8-way, 4.26e6); reads (fixed slot) stay conflict-free. Same XOR on
//      read cols for slots 4..7. B identity (R11-verified 0-conflict).
// Ledger (8 vm/tile: A4 then B4): entry VMC(4) retires A(J),B(J),A(J+1); leaves
//   B(J+1). LGKM(4)/(8)/(4)/(0) interleave 4x8-MFMA with reads. 1 barrier/tile.

__global__ __launch_bounds__(512)
__attribute__((amdgpu_waves_per_eu(2, 2)))
void gemm_big_kernel(const unsigned short* __restrict__ xb2,
                     const unsigned short* __restrict__ wb2,
                     float* __restrict__ C0,
                     float* __restrict__ C1) {
    __shared__ char lds[163840];   // A ring2 x 32KB @0; B ring3 x 32KB @65536

    const int tid  = threadIdx.x;
    const int lane = tid & 63;
    const int wid  = tid >> 6;
    const int wr   = wid >> 2;          // 0..1
    const int wc   = wid & 3;           // 0..3
    const int l31  = lane & 31;
    const int l5   = lane >> 5;

    const int  kblk = blockIdx.x;
    const int  mb   = blockIdx.y;
    const int  z    = blockIdx.z;
    float* __restrict__ C = z ? C1 : C0;
    const int  kt0  = z * 64;
    const int  jx   = kblk & 7;
    const int  kq   = (kblk >> 3) & 3;

    // ---- A staging: 2 threads/row; row rA=tid>>1, slots g4..g4+3 (g4 = (tid&1)*4)
    const int rA = tid >> 1;
    const int g4 = (tid & 1) * 4;
    const char* xbB = (const char*)xb2 + (long)(mb * 256 + rA) * 128;
    const int o0 = ((g4 + 0) ^ kq) * 16;
    const int o1 = ((g4 + 1) ^ kq) * 16;
    const int o2 = ((g4 + 2) ^ kq) * 16;
    const int o3 = ((g4 + 3) ^ kq) * 16;
    // dest: panel*4096 + slot*512 + ((row&31) ^ (slot&4))*16 ; slot&4 == g4 here
    const int apos = ((rA & 31) ^ g4) * 16;
    const int adw_base = (rA >> 5) * 4096 + apos;
    const int adw0 = adw_base + (g4 + 0) * 512;
    const int adw1 = adw_base + (g4 + 1) * 512;
    const int adw2 = adw_base + (g4 + 2) * 512;
    const int adw3 = adw_base + (g4 + 3) * 512;

    // sign masks mk[q][word], q = slot&3 (block-uniform)
    unsigned int mk[4][4];
#pragma unroll
    for (int q = 0; q < 4; ++q)
#pragma unroll
        for (int w_ = 0; w_ < 4; ++w_) {
            unsigned int m_ = 0;
#pragma unroll
            for (int e2 = 0; e2 < 2; ++e2) {
                int m = 8 * q + 2 * w_ + e2;
                if (gp_sign(m, m ^ kblk) < 0.0f) m_ |= 0x8000u << (16 * e2);
            }
            mk[q][w_] = m_;
        }

    // ---- B staging + fragment bases
    const int  tid16 = tid * 16;
    const char* bSrc = (const char*)wb2 + tid16;
    const int aPan = wr * 16384;            // + mt*4096
    const int bPan = 65536 + wc * 8192;     // + br*32768 + nt*4096

#define B_STAGE(br, ktv) { \
    const long tb_ = (long)(ktv) * 32768; \
    _Pragma("unroll") for (int n = 0; n < 4; ++n) \
        gload_lds16(bSrc + tb_ + n * 8192, lds + 65536 + (br) * 32768 + n * 8192 + tid16); }
#define A_LOAD(ktv) { \
    const char* p_ = xbB + (long)(ktv) * 131072; \
    S0 = *(const bf16x8*)(p_ + o0); \
    S1 = *(const bf16x8*)(p_ + o1); \
    S2 = *(const bf16x8*)(p_ + o2); \
    S3 = *(const bf16x8*)(p_ + o3); }
#define A_SHUF_WRITE(ab) { \
    bf16x8 f0_ = shuffle_sign(S0, jx, mk[0][0], mk[0][1], mk[0][2], mk[0][3]); \
    bf16x8 f1_ = shuffle_sign(S1, jx, mk[1][0], mk[1][1], mk[1][2], mk[1][3]); \
    bf16x8 f2_ = shuffle_sign(S2, jx, mk[2][0], mk[2][1], mk[2][2], mk[2][3]); \
    bf16x8 f3_ = shuffle_sign(S3, jx, mk[3][0], mk[3][1], mk[3][2], mk[3][3]); \
    *(bf16x8*)(lds + (ab) * 32768 + adw0) = f0_; \
    *(bf16x8*)(lds + (ab) * 32768 + adw1) = f1_; \
    *(bf16x8*)(lds + (ab) * 32768 + adw2) = f2_; \
    *(bf16x8*)(lds + (ab) * 32768 + adw3) = f3_; }
// A frag read, slot-pair p: LDS slot s = 2p+l5, col = s*512 + ((l31 ^ (s&4))*16)
#define READ_A(AR, ab, p, xr) { \
    _Pragma("unroll") for (int mt = 0; mt < 4; ++mt) \
        AR[mt] = *(const bf16x8*)(lds + (ab)*32768 + aPan + mt*4096 \
                                  + (2*(p) + l5)*512 + ((l31 ^ (xr))*16)); }
// B frag read, slot-pair p into bF[nt][p]
#define READ_B(br, p) { \
    _Pragma("unroll") for (int nt = 0; nt < 2; ++nt) \
        bF[nt][p] = *(const bf16x8*)(lds + bPan + (br)*32768 + nt*4096 \
                                     + (2*(p) + l5)*512 + l31*16); }
#define MFG(AR, p) \
    _Pragma("unroll") for (int mt = 0; mt < 4; ++mt) \
    _Pragma("unroll") for (int nt = 0; nt < 2; ++nt) \
        acc[mt][nt] = __builtin_amdgcn_mfma_f32_32x32x16_bf16(AR[mt], bF[nt][p], acc[mt][nt], 0, 0, 0);

    f32x16 acc[4][2];
#pragma unroll
    for (int mt = 0; mt < 4; ++mt)
#pragma unroll
        for (int nt = 0; nt < 2; ++nt) acc[mt][nt] = (f32x16)0.0f;

    bf16x8 S0, S1, S2, S3;
    bf16x8 X[4], Y[4];
    bf16x8 bF[2][4];

    // ---- prologue: abuf0 <- A(0); B(0),B(1) staged; S <- A(1).
    A_LOAD(kt0);
    SCHED0();
    VMC(0);
    A_SHUF_WRITE(0);
    SCHED0();
    B_STAGE(0, kt0);            // B(0) [4]
    SCHED0();
    A_LOAD(kt0 + 1);            // A(1) [8]
    SCHED0();
    B_STAGE(1, kt0 + 1);        // B(1) [12]
    SCHED0();
    LGKM(0);
    BAR();

// tile J: ab=J&1 (read), abW=(J+1)&1 (write), br=J%3, brS=(J+2)%3
#define TILE(Jv, AB, ABW, BRR, BRS) { \
    const int ktp = (kt0 + (Jv) + 2) & 127; \
    VMC(4);                    /* A(J),B(J),A(J+1) retired; B(J+1) in flight */ \
    A_SHUF_WRITE(ABW);         /* 4 dsw: abuf for J+1 */ \
    SCHED0(); \
    READ_B(BRR, 0); READ_B(BRR, 1); \
    READ_A(X, AB, 0, 0); \
    READ_A(Y, AB, 1, 0);       /* lgkm: 4dsw+4B01...+4A0+4A1 = 16 */ \
    SCHED0(); \
    A_LOAD(ktp);               /* 4 vm */ \
    SCHED0(); \
    B_STAGE(BRS, ktp);         /* 4 vm */ \
    SCHED0(); \
    LGKM(4);  MFG(X, 0);       /* dsw+B01+A0 done; A1 pending */ \
    READ_B(BRR, 2); READ_B(BRR, 3); \
    READ_A(X, AB, 2, 4);       /* pending: A1 4 + B23 4 + A2 4 */ \
    SCHED0(); \
    LGKM(8);  MFG(Y, 1);       /* A1 done */ \
    READ_A(Y, AB, 3, 4);       /* pending: B23 4 + A2 4 + A3 4 */ \
    SCHED0(); \
    LGKM(4);  MFG(X, 2);       /* B23,A2 done */ \
    LGKM(0);  MFG(Y, 3); \
    BAR(); }

    for (int t = 0; t < 60; t += 6) {
        TILE(t + 0, 0, 1, 0, 2);
        TILE(t + 1, 1, 0, 1, 0);
        TILE(t + 2, 0, 1, 2, 1);
        TILE(t + 3, 1, 0, 0, 2);
        TILE(t + 4, 0, 1, 1, 0);
        TILE(t + 5, 1, 0, 2, 1);
    }
    TILE(60, 0, 1, 0, 2);
    TILE(61, 1, 0, 1, 0);
    TILE(62, 0, 1, 2, 1);
    TILE(63, 1, 0, 0, 2);

    // ---- epilogue: 32x32 C/D layout col=lane&31, row=(r&3)+8*(r>>2)+4*l5
#pragma unroll
    for (int mt = 0; mt < 4; ++mt)
#pragma unroll
        for (int nt = 0; nt < 2; ++nt) {
            long c = (long)kblk * 256 + wc * 64 + nt * 32 + l31;
#pragma unroll
            for (int r = 0; r < 16; ++r) {
                int  rl = (r & 3) + 8 * (r >> 2) + 4 * l5;
                long rb = (long)mb * 256 + wr * 128 + mt * 32 + rl;
                C[rb * N_DIM + c] = acc[mt][nt][r];
            }
        }

#undef B_STAGE
#undef A_LOAD
#undef A_SHUF_WRITE
#undef READ_A
#undef READ_B
#undef MFG
#undef TILE
}

// ---------- fused transpose + split-K reduce: out[b][o*32+k] = (C0+C1)[b][k*256+o] ----------
__global__ __launch_bounds__(256) void transpose_add_kernel(const float* __restrict__ C0,
                                                            const float* __restrict__ C1,
                                                            float* __restrict__ out) {
    __shared__ float t[32 * 260];
    const int tid = threadIdx.x;
    const long b  = blockIdx.x;
    const float4* s0 = (const float4*)(C0 + b * N_DIM);
    const float4* s1 = (const float4*)(C1 + b * N_DIM);
    float4*       dst = (float4*)(out + b * N_DIM);
#pragma unroll
    for (int r = 0; r < 8; ++r) {
        int f = tid + r * 256;
        float4 v = s0[f], u = s1[f];
        v.x += u.x; v.y += u.y; v.z += u.z; v.w += u.w;
        int k  = f >> 6;
        int c4 = (f & 63) * 4;
        *(float4*)&t[k * 260 + c4] = v;
    }
    __syncthreads();
#pragma unroll
    for (int r = 0; r < 8; ++r) {
        int g  = tid + r * 256;
        int o  = g >> 3;
        int k0 = (g & 7) * 4;
        float4 v;
        v.x = t[(k0 + 0) * 260 + o];
        v.y = t[(k0 + 1) * 260 + o];
        v.z = t[(k0 + 2) * 260 + o];
        v.w = t[(k0 + 3) * 260 + o];
        dst[g] = v;
    }
}

// ---------- fallback (ws tiny): direct fp32, correct but slow ----------
__global__ __launch_bounds__(256) void fallback_gp_kernel(const float* __restrict__ x,
                                                          const float* __restrict__ w,
                                                          float* __restrict__ out) {
    __shared__ float xs[IN_DIM * 32];
    __shared__ float tab[1024];
    int tid = threadIdx.x;
    for (int idx = tid; idx < 1024; idx += 256) {
        int m = idx >> 5, k = idx & 31;
        tab[idx] = gp_sign(m, m ^ k);
    }
    int b = blockIdx.x;
    const float4* xrow = (const float4*)(x + (long)b * K_DIM);
    float4* xs4 = (float4*)xs;
    for (int idx = tid; idx < 2048; idx += 256) xs4[idx] = xrow[idx];
    __syncthreads();

    int wid = tid >> 6, lane = tid & 63;
    int o = blockIdx.y * 8 + wid;
    int k = lane & 31, half = lane >> 5;
    float acc = 0.f;
    const float* wrow = w + (long)o * K_DIM + half * 4096;
    for (int i = 0; i < 128; ++i) {
        int ib = (half * 128 + i) * 32;
#pragma unroll
        for (int m = 0; m < 32; ++m) {
            acc += xs[ib + (m ^ k)] * tab[m * 32 + k] * wrow[i * 32 + m];
        }
    }
    acc += __shfl_down(acc, 32);
    if (half == 0) out[((long)b * OUT_DIM + o) * 32 + k] = acc;
}

// ---------- launch ----------
extern "C" void kernel_launch(void* const* d_in, const int* in_sizes, int n_in,
                              void* d_out, int out_size, void* d_ws, size_t ws_size,
                              hipStream_t stream) {
    const float* x = (const float*)d_in[0];
    const float* w = (const float*)d_in[1];
    float* out = (float*)d_out;

    const size_t xb_bytes = (size_t)B_DIM * K_DIM * 2;           // 16 MiB
    const size_t wb_bytes = (size_t)OUT_DIM * IN_DIM * 32 * 2;   // 4.2 MB
    const size_t cw_bytes = (size_t)B_DIM * N_DIM * 4;           // 32 MiB
    const size_t need = xb_bytes + wb_bytes + 2 * cw_bytes;      // ~84 MB

    if (ws_size >= need) {
        unsigned short* xbp = (unsigned short*)d_ws;
        unsigned short* wbp = (unsigned short*)((char*)d_ws + xb_bytes);
        float* c0 = (float*)((char*)d_ws + xb_bytes + wb_bytes);
        float* c1 = (float*)((char*)d_ws + xb_bytes + wb_bytes + cw_bytes);

        cast_x2_kernel<<<dim3(4096), dim3(256), 0, stream>>>(x, xbp);
        cast_w_perm_kernel<<<dim3(1024), dim3(256), 0, stream>>>(w, wbp);
        gemm_big_kernel<<<dim3(32, 4, 2), dim3(512), 0, stream>>>(xbp, wbp, c0, c1);
        transpose_add_kernel<<<dim3(B_DIM), dim3(256), 0, stream>>>(c0, c1, out);
    } else {
        fallback_gp_kernel<<<dim3(B_DIM, OUT_DIM / 8), dim3(256), 0, stream>>>(x, w, out);
    }
}